// Round 10
// baseline (1507.529 us; speedup 1.0000x reference)
//
#include <hip/hip_runtime.h>
#include <hip/hip_bf16.h>
#include <math.h>

#define T_SEQ 256
#define FEAT  128
#define UNITS 50
#define NG    200   // 4*UNITS
#define OUTD  74
#define BATCH 1024
#define NPAD  224   // 7 strips of 32
#define WPLANE (NPAD * FEAT)   // 28672 elements per Wt plane
#define R4    4     // batch rows per rec5 block

typedef __attribute__((ext_vector_type(8)))  short bf16x8;
typedef __attribute__((ext_vector_type(16))) float f32x16;

__device__ __forceinline__ unsigned short f2bf(float f) {
    unsigned u = __float_as_uint(f);
    return (unsigned short)((u + 0x7fffu + ((u >> 16) & 1u)) >> 16);
}
__device__ __forceinline__ float bf2f(unsigned short h) {
    return __uint_as_float(((unsigned)h) << 16);
}
__device__ __forceinline__ float sigf(float x) {
    return __builtin_amdgcn_rcpf(1.f + __expf(-x));
}

// ---------------------------------------------------------------------------
// Prep: W[128][200] -> W^T hi/lo bf16 [224 cols][128 k], zero-padded cols.
// ---------------------------------------------------------------------------
__global__ __launch_bounds__(256) void prep_w(
    const float* __restrict__ Wf, const float* __restrict__ Wb,
    unsigned short* __restrict__ Wt)
{
    const int idx = blockIdx.x * 256 + threadIdx.x;     // < 28672
    const int dir = blockIdx.y;
    const int col = idx >> 7, k = idx & 127;
    const float* W = dir ? Wb : Wf;
    const float v = (col < NG) ? W[k * NG + col] : 0.f;
    const unsigned short hi = f2bf(v);
    const unsigned short lo = f2bf(v - bf2f(hi));
    Wt[(size_t)(dir * 2 + 0) * WPLANE + idx] = hi;
    Wt[(size_t)(dir * 2 + 1) * WPLANE + idx] = lo;
}

// ---------------------------------------------------------------------------
// Prep: window of x -> bf16 hi/lo, layout [B*Tc][128] matching proj M order.
// ---------------------------------------------------------------------------
__global__ __launch_bounds__(256) void prep_x(
    const float* __restrict__ x,
    unsigned short* __restrict__ xh, unsigned short* __restrict__ xl,
    int Tc, int lTc, int t0, int n4)
{
    const int stride = gridDim.x * blockDim.x;
    for (int e4 = blockIdx.x * blockDim.x + threadIdx.x; e4 < n4; e4 += stride) {
        const int row = e4 >> 5, k4 = e4 & 31;
        const int b = row >> lTc, ti = row & (Tc - 1);
        const float4 v = *(const float4*)(x + (((size_t)(b * T_SEQ + t0 + ti)) << 7) + (k4 << 2));
        ushort4 hi, lo;
        hi.x = f2bf(v.x); lo.x = f2bf(v.x - bf2f(hi.x));
        hi.y = f2bf(v.y); lo.y = f2bf(v.y - bf2f(hi.y));
        hi.z = f2bf(v.z); lo.z = f2bf(v.z - bf2f(hi.z));
        hi.w = f2bf(v.w); lo.w = f2bf(v.w - bf2f(hi.w));
        *(ushort4*)(xh + ((size_t)e4 << 2)) = hi;
        *(ushort4*)(xl + ((size_t)e4 << 2)) = lo;
    }
}

// ---------------------------------------------------------------------------
// Projection GEMM via bf16x3 split MFMA (unchanged — proven correct, fast).
// ---------------------------------------------------------------------------
__global__ __launch_bounds__(448, 2) void proj_mfma(
    const unsigned short* __restrict__ xfh, const unsigned short* __restrict__ xfl,
    const unsigned short* __restrict__ xbh, const unsigned short* __restrict__ xbl,
    const unsigned short* __restrict__ Wt,
    float* __restrict__ zf, float* __restrict__ zb,
    int mpb, int nMT)
{
    const int dir = blockIdx.y;
    const unsigned short* __restrict__ Ah_p = dir ? xbh : xfh;
    const unsigned short* __restrict__ Al_p = dir ? xbl : xfl;
    float* __restrict__ z = dir ? zb : zf;
    const unsigned short* __restrict__ Wth = Wt + (size_t)(dir * 2) * WPLANE;
    const unsigned short* __restrict__ Wtl = Wth + WPLANE;

    const int l    = threadIdx.x & 63;
    const int wv   = threadIdx.x >> 6;       // 0..6 strip
    const int ln   = l & 31;
    const int half = l >> 5;
    const int col  = wv * 32 + ln;

    bf16x8 Bh[8], Bl[8];
#pragma unroll
    for (int ks = 0; ks < 8; ++ks) {
        const size_t wo = (size_t)col * 128 + ks * 16 + half * 8;
        Bh[ks] = *(const bf16x8*)(Wth + wo);
        Bl[ks] = *(const bf16x8*)(Wtl + wo);
    }
    const bool colOK = (col < NG);

    int mt = blockIdx.x * mpb;
    bf16x8 Ah[8], Al[8], Ah2[8], Al2[8];
    {
        const size_t ab = ((size_t)(mt * 32 + ln)) << 7;
#pragma unroll
        for (int ks = 0; ks < 8; ++ks) {
            Ah[ks] = *(const bf16x8*)(Ah_p + ab + ks * 16 + half * 8);
            Al[ks] = *(const bf16x8*)(Al_p + ab + ks * 16 + half * 8);
        }
    }

    for (int i = 0; i < mpb; ++i) {
        const int mtn = (i + 1 < mpb) ? (mt + 1) : mt;
        const size_t an = ((size_t)(mtn * 32 + ln)) << 7;
#pragma unroll
        for (int ks = 0; ks < 8; ++ks) {
            Ah2[ks] = *(const bf16x8*)(Ah_p + an + ks * 16 + half * 8);
            Al2[ks] = *(const bf16x8*)(Al_p + an + ks * 16 + half * 8);
        }

        f32x16 acc = {};
#pragma unroll
        for (int ks = 0; ks < 8; ++ks) {
            acc = __builtin_amdgcn_mfma_f32_32x32x16_bf16(Ah[ks], Bh[ks], acc, 0, 0, 0);
            acc = __builtin_amdgcn_mfma_f32_32x32x16_bf16(Ah[ks], Bl[ks], acc, 0, 0, 0);
            acc = __builtin_amdgcn_mfma_f32_32x32x16_bf16(Al[ks], Bh[ks], acc, 0, 0, 0);
        }

        if (colOK) {
            float* zp = z + (size_t)(mt * 32 + half * 4) * NG + col;
#pragma unroll
            for (int r = 0; r < 16; ++r) {
                const int row = (r & 3) + ((r >> 2) << 3);
                zp[(size_t)row * NG] = acc[r];
            }
        }
#pragma unroll
        for (int ks = 0; ks < 8; ++ks) { Ah[ks] = Ah2[ks]; Al[ks] = Al2[ks]; }
        ++mt;
    }
}

// ---------------------------------------------------------------------------
// Recurrence v5: scalar, high-occupancy, LDS-staged U, 4 rows/thread.
// R9 post-mortem: rec4's 64 big blocks left 75% of CUs idle and fully
// exposed the per-step MFMA+barrier latency (4.8us/step). rec3 (2.8us/step)
// was L1-bound re-reading U. rec5: U^T fp32 in LDS [52][200] (lanes
// contiguous -> conflict-free), each thread owns gate col j for R4=4 batch
// rows so every U read feeds 4 FMAs. 512 blocks x 4 waves = 8 waves/CU.
// Recurrence stays exact fp32. ~500 VALU cy/step/wave -> ~27us/chunk.
// ---------------------------------------------------------------------------
__global__ __launch_bounds__(256) void rec5(
    const float* __restrict__ zf, const float* __restrict__ zb,
    const float* __restrict__ Uf, const float* __restrict__ Ub,
    const float* __restrict__ bf_, const float* __restrict__ bb_,
    float* __restrict__ hF, float* __restrict__ cF,
    float* __restrict__ hB, float* __restrict__ cB,
    int Tc, int first)
{
    const int tid = threadIdx.x;
    const int dir = blockIdx.y;
    const int b0  = blockIdx.x * R4;
    const float* __restrict__ z    = dir ? zb : zf;
    const float* __restrict__ U    = dir ? Ub : Uf;
    const float* __restrict__ bias = dir ? bb_ : bf_;
    float* __restrict__ hS = dir ? hB : hF;
    float* __restrict__ cS = dir ? cB : cF;

    __shared__ float Us[52][NG];               // 41.6 KB, U^T rows=k
    __shared__ __align__(16) float hsh[R4][52];
    __shared__ float gsh[R4][NG];

    const bool act = (tid < NG);
    const int  j   = tid;
    const bool isg = (j >= 100) && (j < 150);  // g gate -> relu
    const float bj = act ? bias[j] : 0.f;

    // stage U^T: Us[k][j] = U[k][j]; coalesced read, conflict-free write
    if (act) {
#pragma unroll
        for (int k = 0; k < UNITS; ++k) Us[k][j] = U[k * NG + j];
        Us[50][j] = 0.f;
        Us[51][j] = 0.f;
    }

    // state: update-thread t<200 owns (row ur, unit uu)
    const int ur = tid / UNITS;
    const int uu = tid - ur * UNITS;
    float creg = 0.f;
    if (tid < R4 * UNITS) {
        creg = first ? 0.f : cS[(b0 + ur) * UNITS + uu];
        hsh[ur][uu] = first ? 0.f : hS[(b0 + ur) * UNITS + uu];
    }
    if (tid < R4 * 2) hsh[tid >> 1][50 + (tid & 1)] = 0.f;   // zero k-pad
    __syncthreads();

    const int stp = dir ? -1 : 1;
    int ti = dir ? Tc - 1 : 0;
    int zofs[R4];
#pragma unroll
    for (int r = 0; r < R4; ++r)
        zofs[r] = ((b0 + r) * Tc) * NG + (act ? j : 0);

    float zc[R4] = {0.f, 0.f, 0.f, 0.f};
    float zn[R4];
    if (act) {
#pragma unroll
        for (int r = 0; r < R4; ++r) zc[r] = z[zofs[r] + ti * NG];
    }

    for (int tt = 0; tt < Tc; ++tt) {
        const int tin = ti + stp;
#pragma unroll
        for (int r = 0; r < R4; ++r) zn[r] = 0.f;
        if (tt + 1 < Tc && act) {
#pragma unroll
            for (int r = 0; r < R4; ++r) zn[r] = z[zofs[r] + tin * NG];
        }

        float a0 = zc[0] + bj, a1 = zc[1] + bj;
        float a2 = zc[2] + bj, a3 = zc[3] + bj;
#pragma unroll
        for (int k4 = 0; k4 < 13; ++k4) {
            const float4 h0 = *(const float4*)&hsh[0][k4 * 4];   // broadcast
            const float4 h1 = *(const float4*)&hsh[1][k4 * 4];
            const float4 h2 = *(const float4*)&hsh[2][k4 * 4];
            const float4 h3 = *(const float4*)&hsh[3][k4 * 4];
            const float u0 = Us[k4 * 4 + 0][j];                  // conflict-free
            const float u1 = Us[k4 * 4 + 1][j];
            const float u2 = Us[k4 * 4 + 2][j];
            const float u3 = Us[k4 * 4 + 3][j];
            a0 = fmaf(h0.x, u0, a0); a1 = fmaf(h1.x, u0, a1);
            a2 = fmaf(h2.x, u0, a2); a3 = fmaf(h3.x, u0, a3);
            a0 = fmaf(h0.y, u1, a0); a1 = fmaf(h1.y, u1, a1);
            a2 = fmaf(h2.y, u1, a2); a3 = fmaf(h3.y, u1, a3);
            a0 = fmaf(h0.z, u2, a0); a1 = fmaf(h1.z, u2, a1);
            a2 = fmaf(h2.z, u2, a2); a3 = fmaf(h3.z, u2, a3);
            a0 = fmaf(h0.w, u3, a0); a1 = fmaf(h1.w, u3, a1);
            a2 = fmaf(h2.w, u3, a2); a3 = fmaf(h3.w, u3, a3);
        }

        if (act) {
            gsh[0][j] = isg ? fmaxf(a0, 0.f) : sigf(a0);
            gsh[1][j] = isg ? fmaxf(a1, 0.f) : sigf(a1);
            gsh[2][j] = isg ? fmaxf(a2, 0.f) : sigf(a2);
            gsh[3][j] = isg ? fmaxf(a3, 0.f) : sigf(a3);
        }
        __syncthreads();

        if (tid < R4 * UNITS) {
            const float gi = gsh[ur][uu];
            const float gf = gsh[ur][50 + uu];
            const float gg = gsh[ur][100 + uu];
            const float go = gsh[ur][150 + uu];
            creg = fmaf(gf, creg, gi * gg);
            hsh[ur][uu] = go * fmaxf(creg, 0.f);
        }
        __syncthreads();

#pragma unroll
        for (int r = 0; r < R4; ++r) zc[r] = zn[r];
        ti = tin;
    }

    if (tid < R4 * UNITS) {
        hS[(b0 + ur) * UNITS + uu] = hsh[ur][uu];
        cS[(b0 + ur) * UNITS + uu] = creg;
    }
}

// ---------------------------------------------------------------------------
// Head: logits = [h_f, h_b] @ W_d + b_d ; softmax. One block per batch row.
// ---------------------------------------------------------------------------
__global__ __launch_bounds__(128) void head_kernel(
    const float* __restrict__ hF, const float* __restrict__ hB,
    const float* __restrict__ Wd, const float* __restrict__ bd,
    float* __restrict__ out)
{
    const int b   = blockIdx.x;
    const int tid = threadIdx.x;
    __shared__ float hsh[100];
    __shared__ float red[128];

    if (tid < 50) {
        hsh[tid]      = hF[b * 50 + tid];
        hsh[50 + tid] = hB[b * 50 + tid];
    }
    __syncthreads();

    float logit = -INFINITY;
    if (tid < OUTD) {
        float acc = bd[tid];
#pragma unroll 4
        for (int k = 0; k < 100; ++k) acc = fmaf(hsh[k], Wd[k * OUTD + tid], acc);
        logit = acc;
    }
    red[tid] = logit;
    __syncthreads();
    for (int s = 64; s > 0; s >>= 1) {
        if (tid < s) red[tid] = fmaxf(red[tid], red[tid + s]);
        __syncthreads();
    }
    const float m = red[0];
    __syncthreads();
    const float e = (tid < OUTD) ? expf(logit - m) : 0.f;
    red[tid] = e;
    __syncthreads();
    for (int s = 64; s > 0; s >>= 1) {
        if (tid < s) red[tid] += red[tid + s];
        __syncthreads();
    }
    if (tid < OUTD) out[b * OUTD + tid] = e / red[0];
}

// ---------------------------------------------------------------------------
extern "C" void kernel_launch(void* const* d_in, const int* in_sizes, int n_in,
                              void* d_out, int out_size, void* d_ws, size_t ws_size,
                              hipStream_t stream)
{
    const float* x  = (const float*)d_in[0];
    const float* Wf = (const float*)d_in[1];
    const float* Uf = (const float*)d_in[2];
    const float* bf = (const float*)d_in[3];
    const float* Wb = (const float*)d_in[4];
    const float* Ub = (const float*)d_in[5];
    const float* bb = (const float*)d_in[6];
    const float* Wd = (const float*)d_in[7];
    const float* bd = (const float*)d_in[8];
    float* out = (float*)d_out;

    auto aln = [](size_t v) { return (v + 255) & ~(size_t)255; };

    // choose largest time chunk that fits in workspace
    int Tc = T_SEQ;
    bool shx = true;
    for (;;) {
        shx = (Tc == T_SEQ);
        const size_t zsz = aln((size_t)BATCH * Tc * NG * 4);
        const size_t xsz = aln((size_t)BATCH * Tc * FEAT * 2);
        const size_t need = 2 * zsz + (shx ? 2 : 4) * xsz
                          + aln(4 * WPLANE * 2)
                          + aln(4ull * BATCH * UNITS * 4);
        if (need <= ws_size || Tc == 8) break;
        Tc >>= 1;
    }
    const int lTc = __builtin_ctz((unsigned)Tc);
    const size_t zsz = aln((size_t)BATCH * Tc * NG * 4);
    const size_t xsz = aln((size_t)BATCH * Tc * FEAT * 2);

    char* p = (char*)d_ws;
    float* zf = (float*)p; p += zsz;
    float* zb = (float*)p; p += zsz;
    unsigned short* xfh = (unsigned short*)p; p += xsz;
    unsigned short* xfl = (unsigned short*)p; p += xsz;
    unsigned short* xbh = xfh;
    unsigned short* xbl = xfl;
    if (!shx) {
        xbh = (unsigned short*)p; p += xsz;
        xbl = (unsigned short*)p; p += xsz;
    }
    unsigned short* Wt = (unsigned short*)p; p += aln(4 * WPLANE * 2);
    float* st = (float*)p;
    float* hF = st;
    float* cF = st + BATCH * UNITS;
    float* hB = st + 2 * BATCH * UNITS;
    float* cB = st + 3 * BATCH * UNITS;

    prep_w<<<dim3(WPLANE / 256, 2), 256, 0, stream>>>(Wf, Wb, Wt);

    const int n4  = BATCH * Tc * 32;          // float4 groups per x window
    const int nMT = BATCH * Tc / 32;          // 32-row M-tiles
    const int NBLK = (nMT < 512) ? nMT : 512;
    const int mpb = nMT / NBLK;
    const int nc  = T_SEQ / Tc;

    for (int c = 0; c < nc; ++c) {
        const int t0f = c * Tc;
        const int t0b = T_SEQ - (c + 1) * Tc;
        prep_x<<<2048, 256, 0, stream>>>(x, xfh, xfl, Tc, lTc, t0f, n4);
        if (!shx)
            prep_x<<<2048, 256, 0, stream>>>(x, xbh, xbl, Tc, lTc, t0b, n4);
        proj_mfma<<<dim3(NBLK, 2), 448, 0, stream>>>(
            xfh, xfl, xbh, xbl, Wt, zf, zb, mpb, nMT);
        rec5<<<dim3(BATCH / R4, 2), 256, 0, stream>>>(
            zf, zb, Uf, Ub, bf, bb, hF, cF, hB, cB, Tc, c == 0);
    }
    head_kernel<<<BATCH, 128, 0, stream>>>(hF, hB, Wd, bd, out);
}

// Round 12
// 944.507 us; speedup vs baseline: 1.5961x; 1.5961x over previous
//
#include <hip/hip_runtime.h>
#include <hip/hip_bf16.h>
#include <math.h>

#define T_SEQ 256
#define FEAT  128
#define UNITS 50
#define NG    200   // 4*UNITS
#define OUTD  74
#define BATCH 1024
#define NPAD  224   // 7 strips of 32
#define WPLANE (NPAD * FEAT)   // 28672 elements per Wt plane

typedef __attribute__((ext_vector_type(8)))  short bf16x8;
typedef __attribute__((ext_vector_type(16))) float f32x16;

__device__ __forceinline__ unsigned short f2bf(float f) {
    unsigned u = __float_as_uint(f);
    return (unsigned short)((u + 0x7fffu + ((u >> 16) & 1u)) >> 16);
}
__device__ __forceinline__ float bf2f(unsigned short h) {
    return __uint_as_float(((unsigned)h) << 16);
}
__device__ __forceinline__ float sigf(float x) {
    return __builtin_amdgcn_rcpf(1.f + __expf(-x));
}

// ---------------------------------------------------------------------------
// Prep: W[128][200] -> W^T hi/lo bf16 [224 cols][128 k], zero-padded cols.
// ---------------------------------------------------------------------------
__global__ __launch_bounds__(256) void prep_w(
    const float* __restrict__ Wf, const float* __restrict__ Wb,
    unsigned short* __restrict__ Wt)
{
    const int idx = blockIdx.x * 256 + threadIdx.x;     // < 28672
    const int dir = blockIdx.y;
    const int col = idx >> 7, k = idx & 127;
    const float* W = dir ? Wb : Wf;
    const float v = (col < NG) ? W[k * NG + col] : 0.f;
    const unsigned short hi = f2bf(v);
    const unsigned short lo = f2bf(v - bf2f(hi));
    Wt[(size_t)(dir * 2 + 0) * WPLANE + idx] = hi;
    Wt[(size_t)(dir * 2 + 1) * WPLANE + idx] = lo;
}

// ---------------------------------------------------------------------------
// Prep: window of x -> bf16 hi/lo, layout [B*Tc][128] matching proj M order.
// ---------------------------------------------------------------------------
__global__ __launch_bounds__(256) void prep_x(
    const float* __restrict__ x,
    unsigned short* __restrict__ xh, unsigned short* __restrict__ xl,
    int Tc, int lTc, int t0, int n4)
{
    const int stride = gridDim.x * blockDim.x;
    for (int e4 = blockIdx.x * blockDim.x + threadIdx.x; e4 < n4; e4 += stride) {
        const int row = e4 >> 5, k4 = e4 & 31;
        const int b = row >> lTc, ti = row & (Tc - 1);
        const float4 v = *(const float4*)(x + (((size_t)(b * T_SEQ + t0 + ti)) << 7) + (k4 << 2));
        ushort4 hi, lo;
        hi.x = f2bf(v.x); lo.x = f2bf(v.x - bf2f(hi.x));
        hi.y = f2bf(v.y); lo.y = f2bf(v.y - bf2f(hi.y));
        hi.z = f2bf(v.z); lo.z = f2bf(v.z - bf2f(hi.z));
        hi.w = f2bf(v.w); lo.w = f2bf(v.w - bf2f(hi.w));
        *(ushort4*)(xh + ((size_t)e4 << 2)) = hi;
        *(ushort4*)(xl + ((size_t)e4 << 2)) = lo;
    }
}

// ---------------------------------------------------------------------------
// Projection GEMM via bf16x3 split MFMA (unchanged — proven correct, fast).
// ---------------------------------------------------------------------------
__global__ __launch_bounds__(448, 2) void proj_mfma(
    const unsigned short* __restrict__ xfh, const unsigned short* __restrict__ xfl,
    const unsigned short* __restrict__ xbh, const unsigned short* __restrict__ xbl,
    const unsigned short* __restrict__ Wt,
    float* __restrict__ zf, float* __restrict__ zb,
    int mpb, int nMT)
{
    const int dir = blockIdx.y;
    const unsigned short* __restrict__ Ah_p = dir ? xbh : xfh;
    const unsigned short* __restrict__ Al_p = dir ? xbl : xfl;
    float* __restrict__ z = dir ? zb : zf;
    const unsigned short* __restrict__ Wth = Wt + (size_t)(dir * 2) * WPLANE;
    const unsigned short* __restrict__ Wtl = Wth + WPLANE;

    const int l    = threadIdx.x & 63;
    const int wv   = threadIdx.x >> 6;       // 0..6 strip
    const int ln   = l & 31;
    const int half = l >> 5;
    const int col  = wv * 32 + ln;

    bf16x8 Bh[8], Bl[8];
#pragma unroll
    for (int ks = 0; ks < 8; ++ks) {
        const size_t wo = (size_t)col * 128 + ks * 16 + half * 8;
        Bh[ks] = *(const bf16x8*)(Wth + wo);
        Bl[ks] = *(const bf16x8*)(Wtl + wo);
    }
    const bool colOK = (col < NG);

    int mt = blockIdx.x * mpb;
    bf16x8 Ah[8], Al[8], Ah2[8], Al2[8];
    {
        const size_t ab = ((size_t)(mt * 32 + ln)) << 7;
#pragma unroll
        for (int ks = 0; ks < 8; ++ks) {
            Ah[ks] = *(const bf16x8*)(Ah_p + ab + ks * 16 + half * 8);
            Al[ks] = *(const bf16x8*)(Al_p + ab + ks * 16 + half * 8);
        }
    }

    for (int i = 0; i < mpb; ++i) {
        const int mtn = (i + 1 < mpb) ? (mt + 1) : mt;
        const size_t an = ((size_t)(mtn * 32 + ln)) << 7;
#pragma unroll
        for (int ks = 0; ks < 8; ++ks) {
            Ah2[ks] = *(const bf16x8*)(Ah_p + an + ks * 16 + half * 8);
            Al2[ks] = *(const bf16x8*)(Al_p + an + ks * 16 + half * 8);
        }

        f32x16 acc = {};
#pragma unroll
        for (int ks = 0; ks < 8; ++ks) {
            acc = __builtin_amdgcn_mfma_f32_32x32x16_bf16(Ah[ks], Bh[ks], acc, 0, 0, 0);
            acc = __builtin_amdgcn_mfma_f32_32x32x16_bf16(Ah[ks], Bl[ks], acc, 0, 0, 0);
            acc = __builtin_amdgcn_mfma_f32_32x32x16_bf16(Al[ks], Bh[ks], acc, 0, 0, 0);
        }

        if (colOK) {
            float* zp = z + (size_t)(mt * 32 + half * 4) * NG + col;
#pragma unroll
            for (int r = 0; r < 16; ++r) {
                const int row = (r & 3) + ((r >> 2) << 3);
                zp[(size_t)row * NG] = acc[r];
            }
        }
#pragma unroll
        for (int ks = 0; ks < 8; ++ks) { Ah[ks] = Ah2[ks]; Al[ks] = Al2[ks]; }
        ++mt;
    }
}

// ---------------------------------------------------------------------------
// Recurrence v6: rec3 structure + inline-asm REGISTER PIN on U.
// History: rec2/rec3 -> allocator sank/remat'd the U loads into the loop
// (VGPR_Count=32 regardless of launch bounds) -> L1-BW-bound 2.8us/step.
// rec4 (MFMA, 64 blocks) -> latency-exposed, 4.8us/step. rec5 (U in LDS,
// 46KB) -> 1 block/CU residency, 7.2us/step.
// Fix here: asm volatile("" : "+v"(Ur[k])) marks each loaded U value as
// asm-produced -> NOT rematerializable -> must stay in a VGPR. LDS stays
// 1KB, grid 2048 blocks, recurrence exact fp32.
// Decisive check: VGPR_Count >= ~96 (if still 32, the pin failed).
// ---------------------------------------------------------------------------
__global__ __launch_bounds__(256, 4) void rec6(
    const float* __restrict__ zf, const float* __restrict__ zb,
    const float* __restrict__ Uf, const float* __restrict__ Ub,
    const float* __restrict__ bf_, const float* __restrict__ bb_,
    float* __restrict__ hF, float* __restrict__ cF,
    float* __restrict__ hB, float* __restrict__ cB,
    int Tc, int first)
{
    const int j = threadIdx.x;
    const int b = blockIdx.x, dir = blockIdx.y;
    const float* __restrict__ z    = dir ? zb : zf;
    const float* __restrict__ U    = dir ? Ub : Uf;
    const float* __restrict__ bias = dir ? bb_ : bf_;
    float* __restrict__ hS = dir ? hB : hF;
    float* __restrict__ cS = dir ? cB : cF;
    const bool act = (j < NG);
    const bool isg = (j >= 100) && (j < 150);   // g-gate columns use relu

    float Ur[50];
#pragma unroll
    for (int k = 0; k < 50; ++k) Ur[k] = act ? U[k * NG + j] : 0.f;
    // --- pin: force each U coefficient to live in a VGPR ---
#pragma unroll
    for (int k = 0; k < 50; ++k) asm volatile("" : "+v"(Ur[k]));

    const float bj = act ? bias[j] : 0.f;

    __shared__ __align__(16) float hsh[52];
    __shared__ float gsh[NG];

    float c = 0.f;
    if (j < 50) {
        c      = first ? 0.f : cS[b * 50 + j];
        hsh[j] = first ? 0.f : hS[b * 50 + j];
    }
    if (j >= 50 && j < 52) hsh[j] = 0.f;
    __syncthreads();

    const int stp = dir ? -1 : 1;
    int ti = dir ? (Tc - 1) : 0;
    const float* __restrict__ zr = z + (size_t)b * Tc * NG;

    float zc = act ? zr[(size_t)ti * NG + j] : 0.f;

    for (int tt = 0; tt < Tc; ++tt) {
        const int tin = ti + stp;
        float zn = 0.f;
        if (tt + 1 < Tc && act) zn = zr[(size_t)tin * NG + j];  // prefetch

        float a = zc + bj;
#pragma unroll
        for (int k4 = 0; k4 < 12; ++k4) {
            const float4 h4 = *(const float4*)(hsh + (k4 << 2));  // broadcast
            a = fmaf(h4.x, Ur[k4 * 4 + 0], a);
            a = fmaf(h4.y, Ur[k4 * 4 + 1], a);
            a = fmaf(h4.z, Ur[k4 * 4 + 2], a);
            a = fmaf(h4.w, Ur[k4 * 4 + 3], a);
        }
        {
            const float2 h2 = *(const float2*)(hsh + 48);
            a = fmaf(h2.x, Ur[48], a);
            a = fmaf(h2.y, Ur[49], a);
        }

        const float s = sigf(a);
        const float r = fmaxf(a, 0.f);
        if (act) gsh[j] = isg ? r : s;
        __syncthreads();

        if (j < 50) {
            const float gi = gsh[j];
            const float gf = gsh[50 + j];
            const float gg = gsh[100 + j];
            const float go = gsh[150 + j];
            c = fmaf(gf, c, gi * gg);
            hsh[j] = go * fmaxf(c, 0.f);
        }
        __syncthreads();

        zc = zn;
        ti = tin;
    }

    if (j < 50) {
        hS[b * 50 + j] = hsh[j];
        cS[b * 50 + j] = c;
    }
}

// ---------------------------------------------------------------------------
// Head: logits = [h_f, h_b] @ W_d + b_d ; softmax. One block per batch row.
// ---------------------------------------------------------------------------
__global__ __launch_bounds__(128) void head_kernel(
    const float* __restrict__ hF, const float* __restrict__ hB,
    const float* __restrict__ Wd, const float* __restrict__ bd,
    float* __restrict__ out)
{
    const int b   = blockIdx.x;
    const int tid = threadIdx.x;
    __shared__ float hsh[100];
    __shared__ float red[128];

    if (tid < 50) {
        hsh[tid]      = hF[b * 50 + tid];
        hsh[50 + tid] = hB[b * 50 + tid];
    }
    __syncthreads();

    float logit = -INFINITY;
    if (tid < OUTD) {
        float acc = bd[tid];
#pragma unroll 4
        for (int k = 0; k < 100; ++k) acc = fmaf(hsh[k], Wd[k * OUTD + tid], acc);
        logit = acc;
    }
    red[tid] = logit;
    __syncthreads();
    for (int s = 64; s > 0; s >>= 1) {
        if (tid < s) red[tid] = fmaxf(red[tid], red[tid + s]);
        __syncthreads();
    }
    const float m = red[0];
    __syncthreads();
    const float e = (tid < OUTD) ? expf(logit - m) : 0.f;
    red[tid] = e;
    __syncthreads();
    for (int s = 64; s > 0; s >>= 1) {
        if (tid < s) red[tid] += red[tid + s];
        __syncthreads();
    }
    if (tid < OUTD) out[b * OUTD + tid] = e / red[0];
}

// ---------------------------------------------------------------------------
extern "C" void kernel_launch(void* const* d_in, const int* in_sizes, int n_in,
                              void* d_out, int out_size, void* d_ws, size_t ws_size,
                              hipStream_t stream)
{
    const float* x  = (const float*)d_in[0];
    const float* Wf = (const float*)d_in[1];
    const float* Uf = (const float*)d_in[2];
    const float* bf = (const float*)d_in[3];
    const float* Wb = (const float*)d_in[4];
    const float* Ub = (const float*)d_in[5];
    const float* bb = (const float*)d_in[6];
    const float* Wd = (const float*)d_in[7];
    const float* bd = (const float*)d_in[8];
    float* out = (float*)d_out;

    auto aln = [](size_t v) { return (v + 255) & ~(size_t)255; };

    // choose largest time chunk that fits in workspace
    int Tc = T_SEQ;
    bool shx = true;
    for (;;) {
        shx = (Tc == T_SEQ);
        const size_t zsz = aln((size_t)BATCH * Tc * NG * 4);
        const size_t xsz = aln((size_t)BATCH * Tc * FEAT * 2);
        const size_t need = 2 * zsz + (shx ? 2 : 4) * xsz
                          + aln(4 * WPLANE * 2)
                          + aln(4ull * BATCH * UNITS * 4);
        if (need <= ws_size || Tc == 8) break;
        Tc >>= 1;
    }
    const int lTc = __builtin_ctz((unsigned)Tc);
    const size_t zsz = aln((size_t)BATCH * Tc * NG * 4);
    const size_t xsz = aln((size_t)BATCH * Tc * FEAT * 2);

    char* p = (char*)d_ws;
    float* zf = (float*)p; p += zsz;
    float* zb = (float*)p; p += zsz;
    unsigned short* xfh = (unsigned short*)p; p += xsz;
    unsigned short* xfl = (unsigned short*)p; p += xsz;
    unsigned short* xbh = xfh;
    unsigned short* xbl = xfl;
    if (!shx) {
        xbh = (unsigned short*)p; p += xsz;
        xbl = (unsigned short*)p; p += xsz;
    }
    unsigned short* Wt = (unsigned short*)p; p += aln(4 * WPLANE * 2);
    float* st = (float*)p;
    float* hF = st;
    float* cF = st + BATCH * UNITS;
    float* hB = st + 2 * BATCH * UNITS;
    float* cB = st + 3 * BATCH * UNITS;

    prep_w<<<dim3(WPLANE / 256, 2), 256, 0, stream>>>(Wf, Wb, Wt);

    const int n4  = BATCH * Tc * 32;          // float4 groups per x window
    const int nMT = BATCH * Tc / 32;          // 32-row M-tiles
    const int NBLK = (nMT < 512) ? nMT : 512;
    const int mpb = nMT / NBLK;
    const int nc  = T_SEQ / Tc;

    for (int c = 0; c < nc; ++c) {
        const int t0f = c * Tc;
        const int t0b = T_SEQ - (c + 1) * Tc;
        prep_x<<<2048, 256, 0, stream>>>(x, xfh, xfl, Tc, lTc, t0f, n4);
        if (!shx)
            prep_x<<<2048, 256, 0, stream>>>(x, xbh, xbl, Tc, lTc, t0b, n4);
        proj_mfma<<<dim3(NBLK, 2), 448, 0, stream>>>(
            xfh, xfl, xbh, xbl, Wt, zf, zb, mpb, nMT);
        rec6<<<dim3(BATCH, 2), 256, 0, stream>>>(
            zf, zb, Uf, Ub, bf, bb, hF, cF, hB, cB, Tc, c == 0);
    }
    head_kernel<<<BATCH, 128, 0, stream>>>(hF, hB, Wd, bd, out);
}